// Round 9
// baseline (182.500 us; speedup 1.0000x reference)
//
#include <hip/hip_runtime.h>
#include <math.h>

// Problem constants (B,N,D)=(8,2048,256), S=128, H=512, E=2H+S=1152
#define BB 8
#define NN 2048
#define DD 256
#define SS 128
#define HH 512
#define EE 1152

typedef short bf16x8 __attribute__((ext_vector_type(8)));
typedef float f32x4 __attribute__((ext_vector_type(4)));

__device__ __forceinline__ short f2bf(float f) {
    union { float f; unsigned u; } a; a.f = f;
    unsigned r = a.u + 0x7FFFu + ((a.u >> 16) & 1u);  // RNE
    return (short)(r >> 16);
}
__device__ __forceinline__ float bf2f(short s) {
    union { unsigned u; float f; } a; a.u = ((unsigned)(unsigned short)s) << 16;
    return a.f;
}
// async global->LDS, 16B per lane; lds dest = wave-uniform base + lane*16
__device__ __forceinline__ void gl_lds16(const short* g, short* l) {
    __builtin_amdgcn_global_load_lds(
        (const __attribute__((address_space(1))) void*)g,
        (__attribute__((address_space(3))) void*)l, 16, 0, 0);
}

// ---------------- K1: fused RMS norm + weight prep (one launch) ------------
__global__ __launch_bounds__(256) void k_pre(
        const float* __restrict__ x, const float* __restrict__ gp,
        short* __restrict__ xn,
        const float* __restrict__ Wuv, const float* __restrict__ Wo,
        short* __restrict__ Wuv_t, short* __restrict__ Wo_t) {
    __shared__ float tile[32][33];
    int bid = blockIdx.x;
    int t = threadIdx.x;
    if (bid < 4096) {
        int wave = t >> 6, lane = t & 63;
        long row = (long)bid * 4 + wave;
        float4 xv = ((const float4*)(x + row * DD))[lane];
        float ss = xv.x*xv.x + xv.y*xv.y + xv.z*xv.z + xv.w*xv.w;
        #pragma unroll
        for (int off = 32; off > 0; off >>= 1) ss += __shfl_down(ss, off);
        ss = __shfl(ss, 0);
        float norm = sqrtf(ss) * 0.0625f;              // ||x|| / sqrt(256)
        float scale = gp[0] / fmaxf(norm, 1e-5f);
        short4 o;
        o.x = f2bf(xv.x * scale); o.y = f2bf(xv.y * scale);
        o.z = f2bf(xv.z * scale); o.w = f2bf(xv.w * scale);
        ((short4*)(xn + row * DD))[lane] = o;
    } else if (bid < 4384) {
        int bid2 = bid - 4096;                // 36 e-tiles x 8 d-tiles
        int et = bid2 % 36, dt = bid2 / 36;
        #pragma unroll
        for (int i = 0; i < 4; i++) {
            int idx = t + i*256, r = idx >> 5, c = idx & 31;
            tile[r][c] = Wuv[(long)(dt*32 + r)*EE + et*32 + c];
        }
        __syncthreads();
        #pragma unroll
        for (int i = 0; i < 4; i++) {
            int idx = t + i*256, r = idx >> 5, c = idx & 31;
            Wuv_t[(long)(et*32 + r)*DD + dt*32 + c] = f2bf(tile[c][r]);
        }
    } else {
        int bid3 = bid - 4384;                // 16 h-tiles x 8 d-tiles
        int ht = bid3 % 16, dt = bid3 / 16;
        #pragma unroll
        for (int i = 0; i < 4; i++) {
            int idx = t + i*256, r = idx >> 5, c = idx & 31;
            tile[r][c] = Wo[(long)(ht*32 + r)*DD + dt*32 + c];
        }
        __syncthreads();
        #pragma unroll
        for (int i = 0; i < 4; i++) {
            int idx = t + i*256, r = idx >> 5, c = idx & 31;
            Wo_t[(long)(dt*32 + r)*HH + ht*32 + c] = f2bf(tile[c][r]);
        }
    }
}

// ---------------- K3: GEMM1 + silu + LDS-transpose epilogue (v9) -----------
// Main loop = r7 proven (gl_lds16, 128x128 tile). Epilogue REWRITTEN:
// r8 post-mortem says scattered 2B global stores (u: 64 cache lines per wave
// store, 1KB row stride) dominated the stable ~100us residue. Now: acc ->
// bf16 into 128x136 LDS tile T (overlays As/Bs, dynamic smem 34816B),
// barrier, then contiguous row reads -> fully coalesced 16B global stores.
// Region per block (grid y): y<4 -> u; 4<=y<8 -> vfrag frags; y=8 -> q/k
// (gamma/beta applied on readback; gamma=1,beta=0 => bit-identical).
#define AS1(i) (smem1 + (i))
#define BS1(i) (smem1 + 8192 + (i))
#define TT(r)  (smem1 + (r)*136)
__global__ __launch_bounds__(256) void k_gemm1(
        const short* __restrict__ xn, const short* __restrict__ Wuv_t,
        const float* __restrict__ b_uv,
        const float* __restrict__ gamma, const float* __restrict__ beta,
        short* __restrict__ u, short* __restrict__ vfrag,
        short* __restrict__ q, short* __restrict__ k) {
    extern __shared__ __align__(16) short smem1[];
    int m0 = blockIdx.x * 128, n0 = blockIdx.y * 128;
    int t = threadIdx.x, w = t >> 6, lane = t & 63;
    int wr = w & 1, wc = w >> 1, l16 = lane & 15, quad = lane >> 4;
    int lr = lane >> 3, lc = (lane & 7) * 8;   // staging: 8 rows/wave-issue
    f32x4 acc[4][4] = {};
    for (int k0 = 0; k0 < DD; k0 += 64) {
        __syncthreads();
        #pragma unroll
        for (int i = 0; i < 4; i++) {
            int r0 = i*32 + w*8;
            gl_lds16(&xn[(long)(m0 + r0 + lr)*DD + k0 + lc], AS1(r0*64));
            gl_lds16(&Wuv_t[(long)(n0 + r0 + lr)*DD + k0 + lc], BS1(r0*64));
        }
        __syncthreads();
        #pragma unroll
        for (int kk = 0; kk < 2; kk++) {
            bf16x8 a[4], bb[4];
            #pragma unroll
            for (int mt = 0; mt < 4; mt++)
                a[mt] = *(const bf16x8*)AS1((wr*64 + mt*16 + l16)*64 + kk*32 + quad*8);
            #pragma unroll
            for (int nt = 0; nt < 4; nt++)
                bb[nt] = *(const bf16x8*)BS1((wc*64 + nt*16 + l16)*64 + kk*32 + quad*8);
            #pragma unroll
            for (int mt = 0; mt < 4; mt++)
                #pragma unroll
                for (int nt = 0; nt < 4; nt++)
                    acc[mt][nt] = __builtin_amdgcn_mfma_f32_16x16x32_bf16(
                        a[mt], bb[nt], acc[mt][nt], 0,0,0);
        }
    }
    __syncthreads();                  // WAR: last MFMA LDS reads done
    // write phase: T[row=m local][col=e local] = bf16(silu(acc+bias))
    #pragma unroll
    for (int mt = 0; mt < 4; mt++)
    #pragma unroll
    for (int nt = 0; nt < 4; nt++) {
        int col = wc*64 + nt*16 + l16;
        float bias = b_uv[n0 + col];
        #pragma unroll
        for (int r = 0; r < 4; r++) {
            int row = wr*64 + mt*16 + quad*4 + r;
            float xv = acc[mt][nt][r] + bias;
            TT(row)[col] = f2bf(xv / (1.0f + __expf(-xv)));
        }
    }
    __syncthreads();                  // RAW: T visible
    if (n0 < 512) {                   // ---- u region: coalesced row stores
        int row = t >> 1, ch = (t & 1) * 64;
        long gm = m0 + row;
        #pragma unroll
        for (int j = 0; j < 8; j++)
            *(bf16x8*)&u[gm*HH + n0 + ch + j*8] = *(const bf16x8*)&TT(row)[ch + j*8];
    } else if (n0 < 1024) {           // ---- v region: emit vfrag layout
        int h0 = n0 - 512;
        int f = t >> 3, sub = t & 7;  // f: 32 frags (mtl<4, htl<8), 8 thr/frag
        int mtl = f >> 3, htl = f & 7;
        long fbase = (((long)((m0 >> 11)*64 + ((m0 & 2047) >> 5) + mtl) * 32)
                      + (h0 >> 4) + htl) * 512;
        #pragma unroll
        for (int i = 0; i < 8; i++) {
            int l = sub*8 + i, qv = l >> 4, l16v = l & 15;
            bf16x8 o;
            #pragma unroll
            for (int e = 0; e < 8; e++)
                o[e] = TT(mtl*32 + qv*8 + e)[htl*16 + l16v];
            *(bf16x8*)&vfrag[fbase + (long)l*8] = o;   // 16B coalesced
        }
    } else {                          // ---- q/k region: gamma/beta + rows
        int row = t >> 1, ch = (t & 1) * 64;
        long gm = m0 + row;
        #pragma unroll
        for (int j = 0; j < 8; j++) {
            bf16x8 a = *(const bf16x8*)&TT(row)[ch + j*8];
            bf16x8 oq, ok;
            #pragma unroll
            for (int e = 0; e < 8; e++) {
                int si = ch + j*8 + e;
                float val = bf2f(a[e]);
                oq[e] = f2bf(val * gamma[si]      + beta[si]);
                ok[e] = f2bf(val * gamma[SS + si] + beta[SS + si]);
            }
            *(bf16x8*)&q[gm*SS + ch + j*8] = oq;
            *(bf16x8*)&k[gm*SS + ch + j*8] = ok;
        }
    }
}

// ---------------- K5: attention + u-gate + fused GEMM2 (r8, kept) ----------
#define KS(p,row)  (smem + ((p)*32 + (row))*136)
#define PS(p,row)  (smem + 8704 + ((p)*64 + (row))*40)
#define GT(hf,row) (smem + (hf)*16896 + (row)*264)

__global__ __launch_bounds__(512, 2) void k_attn(
        const short* __restrict__ q, const short* __restrict__ k,
        const short* __restrict__ vfrag, const short* __restrict__ u,
        const short* __restrict__ Wo_t, const float* __restrict__ b_o,
        float* __restrict__ out) {
    extern __shared__ __align__(16) short smem[];
    int b = blockIdx.x & 7;                  // batch -> XCD pin
    int i0 = (blockIdx.x >> 3) * 64;
    int t = threadIdx.x, w = t >> 6, lane = t & 63;
    int l16 = lane & 15, quad = lane >> 4;
    int qt = w >> 1, mt = w & 1;             // QK tile assignment
    const short* qb  = q + ((long)b * NN + i0) * SS;
    const short* kb  = k + (long)b * NN * SS;
    const short* vfb = vfrag + (long)b * 64 * 32 * 512;
    const float RS = 0.08838834764831845f;   // 1/sqrt(128)

    int krow = t >> 4, kch = (t & 15) * 8;   // k staging map: 32 rows x 256B

    bf16x8 qf[4];
    #pragma unroll
    for (int kc = 0; kc < 4; kc++)
        qf[kc] = *(const bf16x8*)&qb[(long)(qt*16 + l16)*SS + kc*32 + quad*8];

    // prologue: ks[0] <- tile0; kregB = tile1; kregA = tile2; vfA = vf(tile0)
    *(bf16x8*)&KS(0,krow)[kch] = *(const bf16x8*)&kb[(long)krow*SS + kch];
    bf16x8 kregB = *(const bf16x8*)&kb[(long)(32 + krow)*SS + kch];
    bf16x8 kregA = *(const bf16x8*)&kb[(long)(64 + krow)*SS + kch];
    bf16x8 vfA[4], vfB[4];
    #pragma unroll
    for (int jj = 0; jj < 4; jj++)
        vfA[jj] = *(const bf16x8*)&vfb[((long)(w*4 + jj))*512 + lane*8];
    __syncthreads();

    f32x4 acc[16] = {};
    for (int s = 0; s < 32; s++) {
        // ---------------- iter A: tile 2s, parity 0 ----------------
        {
            f32x4 sc = {};
            #pragma unroll
            for (int kc = 0; kc < 4; kc++) {
                bf16x8 kf = *(const bf16x8*)&KS(0, mt*16 + l16)[kc*32 + quad*8];
                sc = __builtin_amdgcn_mfma_f32_16x16x32_bf16(kf, qf[kc], sc, 0,0,0);
            }
            short4 pw;
            float s0 = fmaxf(sc[0]*RS, 0.f), s1 = fmaxf(sc[1]*RS, 0.f);
            float s2 = fmaxf(sc[2]*RS, 0.f), s3 = fmaxf(sc[3]*RS, 0.f);
            pw.x = f2bf(s0*s0); pw.y = f2bf(s1*s1);
            pw.z = f2bf(s2*s2); pw.w = f2bf(s3*s3);
            *(short4*)&PS(0, qt*16 + l16)[mt*16 + quad*4] = pw;
            *(bf16x8*)&KS(1, krow)[kch] = kregB;       // tile 2s+1 (aged)
            __syncthreads();
            int tk = (2*s + 3 < 64) ? 2*s + 3 : 63;
            kregB = *(const bf16x8*)&kb[(long)(tk*32 + krow)*SS + kch];
            #pragma unroll
            for (int jj = 0; jj < 4; jj++)
                vfB[jj] = *(const bf16x8*)&vfb[((long)(2*s+1)*32 + w*4 + jj)*512 + lane*8];
            bf16x8 af[4];
            #pragma unroll
            for (int qq2 = 0; qq2 < 4; qq2++)
                af[qq2] = *(const bf16x8*)&PS(0, qq2*16 + l16)[quad*8];
            #pragma unroll
            for (int jj = 0; jj < 4; jj++)
                #pragma unroll
                for (int qq2 = 0; qq2 < 4; qq2++)
                    acc[qq2*4 + jj] = __builtin_amdgcn_mfma_f32_16x16x32_bf16(
                        af[qq2], vfA[jj], acc[qq2*4 + jj], 0,0,0);
        }
        // ---------------- iter B: tile 2s+1, parity 1 --------------------
        {
            f32x4 sc = {};
            #pragma unroll
            for (int kc = 0; kc < 4; kc++) {
                bf16x8 kf = *(const bf16x8*)&KS(1, mt*16 + l16)[kc*32 + quad*8];
                sc = __builtin_amdgcn_mfma_f32_16x16x32_bf16(kf, qf[kc], sc, 0,0,0);
            }
            short4 pw;
            float s0 = fmaxf(sc[0]*RS, 0.f), s1 = fmaxf(sc[1]*RS, 0.f);
            float s2 = fmaxf(sc[2]*RS, 0.f), s3 = fmaxf(sc[3]*RS, 0.f);
            pw.x = f2bf(s0*s0); pw.y = f2bf(s1*s1);
            pw.z = f2bf(s2*s2); pw.w = f2bf(s3*s3);
            *(short4*)&PS(1, qt*16 + l16)[mt*16 + quad*4] = pw;
            *(bf16x8*)&KS(0, krow)[kch] = kregA;       // tile 2s+2
            __syncthreads();
            int tk = (2*s + 4 < 64) ? 2*s + 4 : 63;
            kregA = *(const bf16x8*)&kb[(long)(tk*32 + krow)*SS + kch];
            int tv = (2*s + 2 < 64) ? 2*s + 2 : 63;
            #pragma unroll
            for (int jj = 0; jj < 4; jj++)
                vfA[jj] = *(const bf16x8*)&vfb[((long)tv*32 + w*4 + jj)*512 + lane*8];
            bf16x8 af[4];
            #pragma unroll
            for (int qq2 = 0; qq2 < 4; qq2++)
                af[qq2] = *(const bf16x8*)&PS(1, qq2*16 + l16)[quad*8];
            #pragma unroll
            for (int jj = 0; jj < 4; jj++)
                #pragma unroll
                for (int qq2 = 0; qq2 < 4; qq2++)
                    acc[qq2*4 + jj] = __builtin_amdgcn_mfma_f32_16x16x32_bf16(
                        af[qq2], vfB[jj], acc[qq2*4 + jj], 0,0,0);
        }
    }

    // ---- fused GEMM2 epilogue ----
    long rowbase = (long)b * NN + i0;
    __syncthreads();                         // B1: main-loop LDS dead
    {
        int hf = w >> 2;
        int hbase = (w & 3) * 64;
        #pragma unroll
        for (int qq2 = 0; qq2 < 4; qq2++)
        #pragma unroll
        for (int jj = 0; jj < 4; jj++) {
            int gh = w*64 + jj*16 + l16;
            #pragma unroll
            for (int r = 0; r < 4; r++) {
                long grow = rowbase + qq2*16 + quad*4 + r;
                float uval = bf2f(u[grow*HH + gh]);
                GT(hf, qq2*16 + quad*4 + r)[hbase + jj*16 + l16] =
                    f2bf(acc[qq2*4 + jj][r] * uval);
            }
        }
    }
    __syncthreads();                         // B2: writes visible
    f32x4 acc2[4][2] = {};
    #pragma unroll
    for (int p = 0; p < 2; p++) {
        #pragma unroll
        for (int kc = 0; kc < 8; kc++) {
            bf16x8 A[4], Bf[2];
            #pragma unroll
            for (int mt2 = 0; mt2 < 4; mt2++)
                A[mt2] = *(const bf16x8*)&GT(p, mt2*16 + l16)[kc*32 + quad*8];
            #pragma unroll
            for (int nt = 0; nt < 2; nt++)
                Bf[nt] = *(const bf16x8*)&Wo_t[(long)(w*32 + nt*16 + l16)*HH
                                               + p*256 + kc*32 + quad*8];
            #pragma unroll
            for (int mt2 = 0; mt2 < 4; mt2++)
                #pragma unroll
                for (int nt = 0; nt < 2; nt++)
                    acc2[mt2][nt] = __builtin_amdgcn_mfma_f32_16x16x32_bf16(
                        A[mt2], Bf[nt], acc2[mt2][nt], 0,0,0);
        }
    }
    #pragma unroll
    for (int mt2 = 0; mt2 < 4; mt2++)
    #pragma unroll
    for (int nt = 0; nt < 2; nt++)
    #pragma unroll
    for (int r = 0; r < 4; r++) {
        long grow = rowbase + mt2*16 + quad*4 + r;
        int gd = w*32 + nt*16 + l16;
        out[grow*DD + gd] = acc2[mt2][nt][r] + b_o[gd];
    }
}

extern "C" void kernel_launch(void* const* d_in, const int* in_sizes, int n_in,
                              void* d_out, int out_size, void* d_ws, size_t ws_size,
                              hipStream_t stream) {
    const float* x     = (const float*)d_in[0];
    const float* g     = (const float*)d_in[1];
    const float* Wuv   = (const float*)d_in[2];
    const float* b_uv  = (const float*)d_in[3];
    const float* gamma = (const float*)d_in[4];
    const float* beta  = (const float*)d_in[5];
    const float* Wo    = (const float*)d_in[6];
    const float* b_o   = (const float*)d_in[7];
    float* out = (float*)d_out;

    short* ws    = (short*)d_ws;
    short* xn    = ws;                                  // 16384*256
    short* Wuv_t = xn    + (long)16384 * 256;           // 1152*256
    short* Wo_t  = Wuv_t + (long)1152 * 256;            // 256*512
    short* u     = Wo_t  + (long)256 * 512;             // 16384*512
    short* vfrag = u     + (long)16384 * 512;           // 16384*512 (frag layout)
    short* qq    = vfrag + (long)16384 * 512;           // 16384*128
    short* kk    = qq    + (long)16384 * 128;           // 16384*128

    k_pre<<<4512, 256, 0, stream>>>(x, g, xn, Wuv, Wo, Wuv_t, Wo_t);
    k_gemm1<<<dim3(128, 9), 256, 34816, stream>>>(xn, Wuv_t, b_uv, gamma, beta,
                                                  u, vfrag, qq, kk);
    k_attn<<<256, 512, 67584, stream>>>(qq, kk, vfrag, u, Wo_t, b_o, out);
}

// Round 10
// 172.209 us; speedup vs baseline: 1.0598x; 1.0598x over previous
//
#include <hip/hip_runtime.h>
#include <math.h>

// Problem constants (B,N,D)=(8,2048,256), S=128, H=512, E=2H+S=1152
#define BB 8
#define NN 2048
#define DD 256
#define SS 128
#define HH 512
#define EE 1152

typedef short bf16x8 __attribute__((ext_vector_type(8)));
typedef float f32x4 __attribute__((ext_vector_type(4)));

__device__ __forceinline__ short f2bf(float f) {
    union { float f; unsigned u; } a; a.f = f;
    unsigned r = a.u + 0x7FFFu + ((a.u >> 16) & 1u);  // RNE
    return (short)(r >> 16);
}
__device__ __forceinline__ float bf2f(short s) {
    union { unsigned u; float f; } a; a.u = ((unsigned)(unsigned short)s) << 16;
    return a.f;
}
// async global->LDS, 16B per lane; lds dest = wave-uniform base + lane*16
__device__ __forceinline__ void gl_lds16(const short* g, short* l) {
    __builtin_amdgcn_global_load_lds(
        (const __attribute__((address_space(1))) void*)g,
        (__attribute__((address_space(3))) void*)l, 16, 0, 0);
}

// ---------------- K1: fused RMS norm + weight prep (one launch) ------------
__global__ __launch_bounds__(256) void k_pre(
        const float* __restrict__ x, const float* __restrict__ gp,
        short* __restrict__ xn,
        const float* __restrict__ Wuv, const float* __restrict__ Wo,
        short* __restrict__ Wuv_t, short* __restrict__ Wo_t) {
    __shared__ float tile[32][33];
    int bid = blockIdx.x;
    int t = threadIdx.x;
    if (bid < 4096) {
        int wave = t >> 6, lane = t & 63;
        long row = (long)bid * 4 + wave;
        float4 xv = ((const float4*)(x + row * DD))[lane];
        float ss = xv.x*xv.x + xv.y*xv.y + xv.z*xv.z + xv.w*xv.w;
        #pragma unroll
        for (int off = 32; off > 0; off >>= 1) ss += __shfl_down(ss, off);
        ss = __shfl(ss, 0);
        float norm = sqrtf(ss) * 0.0625f;              // ||x|| / sqrt(256)
        float scale = gp[0] / fmaxf(norm, 1e-5f);
        short4 o;
        o.x = f2bf(xv.x * scale); o.y = f2bf(xv.y * scale);
        o.z = f2bf(xv.z * scale); o.w = f2bf(xv.w * scale);
        ((short4*)(xn + row * DD))[lane] = o;
    } else if (bid < 4384) {
        int bid2 = bid - 4096;                // 36 e-tiles x 8 d-tiles
        int et = bid2 % 36, dt = bid2 / 36;
        #pragma unroll
        for (int i = 0; i < 4; i++) {
            int idx = t + i*256, r = idx >> 5, c = idx & 31;
            tile[r][c] = Wuv[(long)(dt*32 + r)*EE + et*32 + c];
        }
        __syncthreads();
        #pragma unroll
        for (int i = 0; i < 4; i++) {
            int idx = t + i*256, r = idx >> 5, c = idx & 31;
            Wuv_t[(long)(et*32 + r)*DD + dt*32 + c] = f2bf(tile[c][r]);
        }
    } else {
        int bid3 = bid - 4384;                // 16 h-tiles x 8 d-tiles
        int ht = bid3 % 16, dt = bid3 / 16;
        #pragma unroll
        for (int i = 0; i < 4; i++) {
            int idx = t + i*256, r = idx >> 5, c = idx & 31;
            tile[r][c] = Wo[(long)(ht*32 + r)*DD + dt*32 + c];
        }
        __syncthreads();
        #pragma unroll
        for (int i = 0; i < 4; i++) {
            int idx = t + i*256, r = idx >> 5, c = idx & 31;
            Wo_t[(long)(dt*32 + r)*HH + ht*32 + c] = f2bf(tile[c][r]);
        }
    }
}

// ---------------- K3: GEMM1 + silu + LDS-transpose epilogue (v10) ----------
// Main loop = r7 proven (gl_lds16, 128x128 tile). r9 post-mortem: the
// "coalesced" epilogue maps were WRONG (row=t>>1 put 64 lanes on 32 rows x
// 1KB stride = still 64 scattered pieces/inst). v10 fixes the maps:
//  u:   chunk c=i*256+t, row=c>>4, col=(c&15)*8 -> 4x256B segments/wave-inst
//  q/k: same map; rows are 256B adjacent -> 1KB fully contiguous per inst
//  vfrag: one wave per 1KB frag, lane writes fbase+lane*8 -> 1KB contiguous;
//         LDS transpose reads XOR e by quad to de-phase banks (8way->2way)
#define AS1(i) (smem1 + (i))
#define BS1(i) (smem1 + 8192 + (i))
#define TT(r)  (smem1 + (r)*136)
__global__ __launch_bounds__(256) void k_gemm1(
        const short* __restrict__ xn, const short* __restrict__ Wuv_t,
        const float* __restrict__ b_uv,
        const float* __restrict__ gamma, const float* __restrict__ beta,
        short* __restrict__ u, short* __restrict__ vfrag,
        short* __restrict__ q, short* __restrict__ k) {
    extern __shared__ __align__(16) short smem1[];
    int m0 = blockIdx.x * 128, n0 = blockIdx.y * 128;
    int t = threadIdx.x, w = t >> 6, lane = t & 63;
    int wr = w & 1, wc = w >> 1, l16 = lane & 15, quad = lane >> 4;
    int lr = lane >> 3, lc = (lane & 7) * 8;   // staging: 8 rows/wave-issue
    f32x4 acc[4][4] = {};
    for (int k0 = 0; k0 < DD; k0 += 64) {
        __syncthreads();
        #pragma unroll
        for (int i = 0; i < 4; i++) {
            int r0 = i*32 + w*8;
            gl_lds16(&xn[(long)(m0 + r0 + lr)*DD + k0 + lc], AS1(r0*64));
            gl_lds16(&Wuv_t[(long)(n0 + r0 + lr)*DD + k0 + lc], BS1(r0*64));
        }
        __syncthreads();
        #pragma unroll
        for (int kk = 0; kk < 2; kk++) {
            bf16x8 a[4], bb[4];
            #pragma unroll
            for (int mt = 0; mt < 4; mt++)
                a[mt] = *(const bf16x8*)AS1((wr*64 + mt*16 + l16)*64 + kk*32 + quad*8);
            #pragma unroll
            for (int nt = 0; nt < 4; nt++)
                bb[nt] = *(const bf16x8*)BS1((wc*64 + nt*16 + l16)*64 + kk*32 + quad*8);
            #pragma unroll
            for (int mt = 0; mt < 4; mt++)
                #pragma unroll
                for (int nt = 0; nt < 4; nt++)
                    acc[mt][nt] = __builtin_amdgcn_mfma_f32_16x16x32_bf16(
                        a[mt], bb[nt], acc[mt][nt], 0,0,0);
        }
    }
    __syncthreads();                  // WAR: last MFMA LDS reads done
    // write phase: T[row=m local][col=e local] = bf16(silu(acc+bias))
    #pragma unroll
    for (int mt = 0; mt < 4; mt++)
    #pragma unroll
    for (int nt = 0; nt < 4; nt++) {
        int col = wc*64 + nt*16 + l16;
        float bias = b_uv[n0 + col];
        #pragma unroll
        for (int r = 0; r < 4; r++) {
            int row = wr*64 + mt*16 + quad*4 + r;
            float xv = acc[mt][nt][r] + bias;
            TT(row)[col] = f2bf(xv / (1.0f + __expf(-xv)));
        }
    }
    __syncthreads();                  // RAW: T visible
    if (n0 < 512) {                   // ---- u region: coalesced row chunks
        #pragma unroll
        for (int i = 0; i < 8; i++) {
            int c = i*256 + t;                 // 2048 16B-chunks
            int row = c >> 4, cc = (c & 15) * 8;
            *(bf16x8*)&u[(long)(m0 + row)*HH + n0 + cc] =
                *(const bf16x8*)&TT(row)[cc];
        }
    } else if (n0 < 1024) {           // ---- v region: wave-per-frag emit
        int h0 = n0 - 512;
        int mt32base = ((m0 >> 11) * 64) + ((m0 & 2047) >> 5);
        #pragma unroll
        for (int i = 0; i < 8; i++) {
            int fr = i*4 + w;                  // 32 frags of 1KB
            int mtl = fr >> 3, htl = fr & 7;
            bf16x8 o;
            #pragma unroll
            for (int ee = 0; ee < 8; ee++) {
                int e = ee ^ quad;             // bank de-phase (bijective)
                o[e] = TT(mtl*32 + quad*8 + e)[htl*16 + l16];
            }
            long fbase = (((long)(mt32base + mtl) * 32) + (h0 >> 4) + htl) * 512;
            *(bf16x8*)&vfrag[fbase + lane*8] = o;   // 1KB contiguous/wave
        }
    } else {                          // ---- q/k region: 1KB contiguous rows
        #pragma unroll
        for (int i = 0; i < 8; i++) {
            int c = i*256 + t;
            int row = c >> 4, cc = (c & 15) * 8;
            bf16x8 a = *(const bf16x8*)&TT(row)[cc];
            bf16x8 oq, ok;
            #pragma unroll
            for (int e = 0; e < 8; e++) {
                int si = cc + e;
                float val = bf2f(a[e]);
                oq[e] = f2bf(val * gamma[si]      + beta[si]);
                ok[e] = f2bf(val * gamma[SS + si] + beta[SS + si]);
            }
            *(bf16x8*)&q[(long)(m0 + row)*SS + cc] = oq;
            *(bf16x8*)&k[(long)(m0 + row)*SS + cc] = ok;
        }
    }
}

// ---------------- K5: attention + u-gate + fused GEMM2 (r8/r9, kept) -------
#define KS(p,row)  (smem + ((p)*32 + (row))*136)
#define PS(p,row)  (smem + 8704 + ((p)*64 + (row))*40)
#define GT(hf,row) (smem + (hf)*16896 + (row)*264)

__global__ __launch_bounds__(512, 2) void k_attn(
        const short* __restrict__ q, const short* __restrict__ k,
        const short* __restrict__ vfrag, const short* __restrict__ u,
        const short* __restrict__ Wo_t, const float* __restrict__ b_o,
        float* __restrict__ out) {
    extern __shared__ __align__(16) short smem[];
    int b = blockIdx.x & 7;                  // batch -> XCD pin
    int i0 = (blockIdx.x >> 3) * 64;
    int t = threadIdx.x, w = t >> 6, lane = t & 63;
    int l16 = lane & 15, quad = lane >> 4;
    int qt = w >> 1, mt = w & 1;             // QK tile assignment
    const short* qb  = q + ((long)b * NN + i0) * SS;
    const short* kb  = k + (long)b * NN * SS;
    const short* vfb = vfrag + (long)b * 64 * 32 * 512;
    const float RS = 0.08838834764831845f;   // 1/sqrt(128)

    int krow = t >> 4, kch = (t & 15) * 8;   // k staging map: 32 rows x 256B

    bf16x8 qf[4];
    #pragma unroll
    for (int kc = 0; kc < 4; kc++)
        qf[kc] = *(const bf16x8*)&qb[(long)(qt*16 + l16)*SS + kc*32 + quad*8];

    // prologue: ks[0] <- tile0; kregB = tile1; kregA = tile2; vfA = vf(tile0)
    *(bf16x8*)&KS(0,krow)[kch] = *(const bf16x8*)&kb[(long)krow*SS + kch];
    bf16x8 kregB = *(const bf16x8*)&kb[(long)(32 + krow)*SS + kch];
    bf16x8 kregA = *(const bf16x8*)&kb[(long)(64 + krow)*SS + kch];
    bf16x8 vfA[4], vfB[4];
    #pragma unroll
    for (int jj = 0; jj < 4; jj++)
        vfA[jj] = *(const bf16x8*)&vfb[((long)(w*4 + jj))*512 + lane*8];
    __syncthreads();

    f32x4 acc[16] = {};
    for (int s = 0; s < 32; s++) {
        // ---------------- iter A: tile 2s, parity 0 ----------------
        {
            f32x4 sc = {};
            #pragma unroll
            for (int kc = 0; kc < 4; kc++) {
                bf16x8 kf = *(const bf16x8*)&KS(0, mt*16 + l16)[kc*32 + quad*8];
                sc = __builtin_amdgcn_mfma_f32_16x16x32_bf16(kf, qf[kc], sc, 0,0,0);
            }
            short4 pw;
            float s0 = fmaxf(sc[0]*RS, 0.f), s1 = fmaxf(sc[1]*RS, 0.f);
            float s2 = fmaxf(sc[2]*RS, 0.f), s3 = fmaxf(sc[3]*RS, 0.f);
            pw.x = f2bf(s0*s0); pw.y = f2bf(s1*s1);
            pw.z = f2bf(s2*s2); pw.w = f2bf(s3*s3);
            *(short4*)&PS(0, qt*16 + l16)[mt*16 + quad*4] = pw;
            *(bf16x8*)&KS(1, krow)[kch] = kregB;       // tile 2s+1 (aged)
            __syncthreads();
            int tk = (2*s + 3 < 64) ? 2*s + 3 : 63;
            kregB = *(const bf16x8*)&kb[(long)(tk*32 + krow)*SS + kch];
            #pragma unroll
            for (int jj = 0; jj < 4; jj++)
                vfB[jj] = *(const bf16x8*)&vfb[((long)(2*s+1)*32 + w*4 + jj)*512 + lane*8];
            bf16x8 af[4];
            #pragma unroll
            for (int qq2 = 0; qq2 < 4; qq2++)
                af[qq2] = *(const bf16x8*)&PS(0, qq2*16 + l16)[quad*8];
            #pragma unroll
            for (int jj = 0; jj < 4; jj++)
                #pragma unroll
                for (int qq2 = 0; qq2 < 4; qq2++)
                    acc[qq2*4 + jj] = __builtin_amdgcn_mfma_f32_16x16x32_bf16(
                        af[qq2], vfA[jj], acc[qq2*4 + jj], 0,0,0);
        }
        // ---------------- iter B: tile 2s+1, parity 1 --------------------
        {
            f32x4 sc = {};
            #pragma unroll
            for (int kc = 0; kc < 4; kc++) {
                bf16x8 kf = *(const bf16x8*)&KS(1, mt*16 + l16)[kc*32 + quad*8];
                sc = __builtin_amdgcn_mfma_f32_16x16x32_bf16(kf, qf[kc], sc, 0,0,0);
            }
            short4 pw;
            float s0 = fmaxf(sc[0]*RS, 0.f), s1 = fmaxf(sc[1]*RS, 0.f);
            float s2 = fmaxf(sc[2]*RS, 0.f), s3 = fmaxf(sc[3]*RS, 0.f);
            pw.x = f2bf(s0*s0); pw.y = f2bf(s1*s1);
            pw.z = f2bf(s2*s2); pw.w = f2bf(s3*s3);
            *(short4*)&PS(1, qt*16 + l16)[mt*16 + quad*4] = pw;
            *(bf16x8*)&KS(0, krow)[kch] = kregA;       // tile 2s+2
            __syncthreads();
            int tk = (2*s + 4 < 64) ? 2*s + 4 : 63;
            kregA = *(const bf16x8*)&kb[(long)(tk*32 + krow)*SS + kch];
            int tv = (2*s + 2 < 64) ? 2*s + 2 : 63;
            #pragma unroll
            for (int jj = 0; jj < 4; jj++)
                vfA[jj] = *(const bf16x8*)&vfb[((long)tv*32 + w*4 + jj)*512 + lane*8];
            bf16x8 af[4];
            #pragma unroll
            for (int qq2 = 0; qq2 < 4; qq2++)
                af[qq2] = *(const bf16x8*)&PS(1, qq2*16 + l16)[quad*8];
            #pragma unroll
            for (int jj = 0; jj < 4; jj++)
                #pragma unroll
                for (int qq2 = 0; qq2 < 4; qq2++)
                    acc[qq2*4 + jj] = __builtin_amdgcn_mfma_f32_16x16x32_bf16(
                        af[qq2], vfB[jj], acc[qq2*4 + jj], 0,0,0);
        }
    }

    // ---- fused GEMM2 epilogue ----
    long rowbase = (long)b * NN + i0;
    __syncthreads();                         // B1: main-loop LDS dead
    {
        int hf = w >> 2;
        int hbase = (w & 3) * 64;
        #pragma unroll
        for (int qq2 = 0; qq2 < 4; qq2++)
        #pragma unroll
        for (int jj = 0; jj < 4; jj++) {
            int gh = w*64 + jj*16 + l16;
            #pragma unroll
            for (int r = 0; r < 4; r++) {
                long grow = rowbase + qq2*16 + quad*4 + r;
                float uval = bf2f(u[grow*HH + gh]);
                GT(hf, qq2*16 + quad*4 + r)[hbase + jj*16 + l16] =
                    f2bf(acc[qq2*4 + jj][r] * uval);
            }
        }
    }
    __syncthreads();                         // B2: writes visible
    f32x4 acc2[4][2] = {};
    #pragma unroll
    for (int p = 0; p < 2; p++) {
        #pragma unroll
        for (int kc = 0; kc < 8; kc++) {
            bf16x8 A[4], Bf[2];
            #pragma unroll
            for (int mt2 = 0; mt2 < 4; mt2++)
                A[mt2] = *(const bf16x8*)&GT(p, mt2*16 + l16)[kc*32 + quad*8];
            #pragma unroll
            for (int nt = 0; nt < 2; nt++)
                Bf[nt] = *(const bf16x8*)&Wo_t[(long)(w*32 + nt*16 + l16)*HH
                                               + p*256 + kc*32 + quad*8];
            #pragma unroll
            for (int mt2 = 0; mt2 < 4; mt2++)
                #pragma unroll
                for (int nt = 0; nt < 2; nt++)
                    acc2[mt2][nt] = __builtin_amdgcn_mfma_f32_16x16x32_bf16(
                        A[mt2], Bf[nt], acc2[mt2][nt], 0,0,0);
        }
    }
    #pragma unroll
    for (int mt2 = 0; mt2 < 4; mt2++)
    #pragma unroll
    for (int nt = 0; nt < 2; nt++)
    #pragma unroll
    for (int r = 0; r < 4; r++) {
        long grow = rowbase + mt2*16 + quad*4 + r;
        int gd = w*32 + nt*16 + l16;
        out[grow*DD + gd] = acc2[mt2][nt][r] + b_o[gd];
    }
}

extern "C" void kernel_launch(void* const* d_in, const int* in_sizes, int n_in,
                              void* d_out, int out_size, void* d_ws, size_t ws_size,
                              hipStream_t stream) {
    const float* x     = (const float*)d_in[0];
    const float* g     = (const float*)d_in[1];
    const float* Wuv   = (const float*)d_in[2];
    const float* b_uv  = (const float*)d_in[3];
    const float* gamma = (const float*)d_in[4];
    const float* beta  = (const float*)d_in[5];
    const float* Wo    = (const float*)d_in[6];
    const float* b_o   = (const float*)d_in[7];
    float* out = (float*)d_out;

    short* ws    = (short*)d_ws;
    short* xn    = ws;                                  // 16384*256
    short* Wuv_t = xn    + (long)16384 * 256;           // 1152*256
    short* Wo_t  = Wuv_t + (long)1152 * 256;            // 256*512
    short* u     = Wo_t  + (long)256 * 512;             // 16384*512
    short* vfrag = u     + (long)16384 * 512;           // 16384*512 (frag layout)
    short* qq    = vfrag + (long)16384 * 512;           // 16384*128
    short* kk    = qq    + (long)16384 * 128;           // 16384*128

    k_pre<<<4512, 256, 0, stream>>>(x, g, xn, Wuv, Wo, Wuv_t, Wo_t);
    k_gemm1<<<dim3(128, 9), 256, 34816, stream>>>(xn, Wuv_t, b_uv, gamma, beta,
                                                  u, vfrag, qq, kk);
    k_attn<<<256, 512, 67584, stream>>>(qq, kk, vfrag, u, Wo_t, b_o, out);
}